// Round 6
// baseline (558.303 us; speedup 1.0000x reference)
//
#include <hip/hip_runtime.h>

#define NM 4096
#define NK 16
#define NC 64

typedef __attribute__((ext_vector_type(8))) short s8v;
typedef __attribute__((ext_vector_type(4))) float f4v;
typedef __attribute__((ext_vector_type(2))) unsigned int u2v;

__device__ __forceinline__ short f2bf(float f) {
  unsigned u = __builtin_bit_cast(unsigned, f);
  u += 0x7fffu + ((u >> 16) & 1u);          // round-to-nearest-even
  return (short)(u >> 16);
}
__device__ __forceinline__ float bf2f(unsigned short s) {
  return __builtin_bit_cast(float, ((unsigned)s) << 16);
}
__device__ __forceinline__ unsigned pk2(float a, float b) {
  return (unsigned)(unsigned short)f2bf(a) | ((unsigned)(unsigned short)f2bf(b) << 16);
}
__device__ __forceinline__ s8v pack8(f4v a, f4v b) {
  s8v r;
  r[0]=f2bf(a[0]); r[1]=f2bf(a[1]); r[2]=f2bf(a[2]); r[3]=f2bf(a[3]);
  r[4]=f2bf(b[0]); r[5]=f2bf(b[1]); r[6]=f2bf(b[2]); r[7]=f2bf(b[3]);
  return r;
}

#define MFMA(a,b,c) __builtin_amdgcn_mfma_f32_16x16x32_bf16((a),(b),(c),0,0,0)

#define HSTRIDE 72                  // shorts per row: 64 + pad, 16B-aligned rows
#define QROWS 8                     // points per wave
#define HB_SHORTS (16*HSTRIDE)      // RT buffer: 16 neighbor rows = 2304 B
#define QB_SHORTS (QROWS*HSTRIDE)   // qa/res buffer: 8 point rows = 1152 B

// ---------------- pre-kernel: fold Wa1 into Wq/Wk/Wp2 (fp32, exact) --------
// ws layout (floats):
//   [    0.. 4095] Wqa1 = Wa1·Wq        (row-major [i][j])
//   [ 4096.. 8191] Wak' = -Wa1·Wk
//   [ 8192..12287] Wap  = Wa1·Wp2
//   [12288..12351] bqa  = Wa1·bq
//   [12352..12415] bc   = ba1 + Wa1·(bp2-bk)
__global__ void precomp_kernel(const float* __restrict__ Wq, const float* __restrict__ bq,
                               const float* __restrict__ Wk, const float* __restrict__ bk,
                               const float* __restrict__ Wp2,const float* __restrict__ bp2,
                               const float* __restrict__ Wa1,const float* __restrict__ ba1,
                               float* __restrict__ ws) {
  const int gid = blockIdx.x * 256 + threadIdx.x;
  if (gid < 3*4096) {
    const int m = gid >> 12, e = gid & 4095, i = e >> 6, j = e & 63;
    const float* R = Wa1 + i*64;
    float s = 0.f;
    if (m == 0)      { for (int l = 0; l < 64; ++l) s += R[l] * Wq [l*64 + j]; }
    else if (m == 1) { for (int l = 0; l < 64; ++l) s -= R[l] * Wk [l*64 + j]; }
    else             { for (int l = 0; l < 64; ++l) s += R[l] * Wp2[l*64 + j]; }
    ws[gid] = s;
  } else if (gid < 3*4096 + 64) {
    const int i = gid - 3*4096;
    const float* R = Wa1 + i*64;
    float s = 0.f;
    for (int l = 0; l < 64; ++l) s += R[l] * bq[l];
    ws[gid] = s;
  } else if (gid < 3*4096 + 128) {
    const int i = gid - (3*4096 + 64);
    const float* R = Wa1 + i*64;
    float s = ba1[i];
    for (int l = 0; l < 64; ++l) s += R[l] * (bp2[l] - bk[l]);
    ws[gid] = s;
  }
}

// ---------------- main kernel ----------------------------------------------
// a1 = relu(qa + x@Wak'^T + p1@Wap^T + bc) ;  qa = raw@Wqa1^T + bqa
// p1 by VALU in C-layout. Wv in register frags. 8 points/wave, 12 waves/CU.
__global__ __launch_bounds__(256, 3)
void lattn_kernel(const float* __restrict__ x,  const float* __restrict__ xyz,
                  const float* __restrict__ Wp1,const float* __restrict__ bp1,
                  const float* __restrict__ Wp2,const float* __restrict__ bp2,
                  const float* __restrict__ Wv, const float* __restrict__ bv,
                  const float* __restrict__ Wa2,const float* __restrict__ ba2,
                  const float* __restrict__ W2, const float* __restrict__ b2,
                  const float* __restrict__ ws,
                  float* __restrict__ out) {
  // LDS mats: 0=Wak'(nat) 1=Wp2(sigma) 2=Wap(sigma) 3=Wa2(sigma)
  __shared__ __align__(16) short wlds[4*8*64*8];     // 32768 B
  __shared__ __align__(16) short qres[4*QB_SHORTS];  // 4608 B (qa, then res)
  __shared__ __align__(16) short hbuf[4*HB_SHORTS];  // 9216 B (RT buffer)
  // total 46592 B -> 3 blocks/CU, 12 waves/CU

  const int tid = threadIdx.x;
  const float* wak = ws + 4096;
  const float* wap = ws + 8192;
  const float* bqa = ws + 12288;
  const float* bcv = ws + 12352;

  // ---- stage 4 weight matrices into LDS, bf16, frag-linear ----
  for (int idx = tid; idx < 4*8*64; idx += 256) {
    const int mat = idx >> 9;
    const int rem = idx & 511;
    const int f   = rem >> 6;
    const int ln  = rem & 63;
    const int t = f >> 1, h = f & 1;
    const int cc = ln & 15, qq = ln >> 4;
    const int n = 16*t + cc;
    const float* W = (mat==0) ? wak : (mat==1) ? Wp2 : (mat==2) ? wap : Wa2;
    const bool prm = (mat >= 1);
    s8v v;
    #pragma unroll
    for (int j = 0; j < 8; ++j) {
      int kp = h*32 + qq*8 + j;
      int k = prm ? (((kp & 3) << 4) | (kp >> 2)) : kp;
      v[j] = f2bf(W[n*64 + k]);
    }
    *(s8v*)&wlds[(size_t)idx * 8] = v;
  }
  __syncthreads();

  const int w    = tid >> 6;
  const int lane = tid & 63;
  const int c    = lane & 15;
  const int lq   = lane >> 4;

  const int gw  = blockIdx.x * 4 + w;   // 0..4095 waves
  const int gp0 = gw << 3;              // 8 points per wave
  const int b   = gp0 >> 12;
  const int m0  = gp0 & (NM - 1);

  short* qbuf = qres + w * QB_SHORTS;
  short* hb   = hbuf + w * HB_SHORTS;

  // ---- loop-invariant: Wv frags (regs), Wp1 rows (C-layout), biases ----
  s8v wvf[8];
  #pragma unroll
  for (int t = 0; t < 4; ++t) {
    const float* wr = Wv + (16*t + c)*64 + 8*lq;
    wvf[2*t+0] = pack8(*(const f4v*)wr,      *(const f4v*)(wr+4));
    wvf[2*t+1] = pack8(*(const f4v*)(wr+32), *(const f4v*)(wr+36));
  }
  float wp1c[4][3];
  float bp1f[4], bvf[4], bp2f[4], ba2f[4], bcf[4];
  #pragma unroll
  for (int t = 0; t < 4; ++t) {
    const int n = 16*t + c;
    wp1c[t][0] = Wp1[n*3+0]; wp1c[t][1] = Wp1[n*3+1]; wp1c[t][2] = Wp1[n*3+2];
    bp1f[t] = bp1[n]; bvf[t] = bv[n]; bp2f[t] = bp2[n];
    ba2f[t] = ba2[n]; bcf[t] = bcv[n];
  }

  const long ptbase = (long)(b * NM + m0);

  // ---- group qa phase: qa = raw @ Wqa1^T + bqa (8 valid rows) ----
  {
    const float* xr = x + (ptbase + (c & 7)) * (long)(NK*NC) + 8*lq;
    s8v rA0 = pack8(*(const f4v*)xr,        *(const f4v*)(xr+4));
    s8v rA1 = pack8(*(const f4v*)(xr+32),   *(const f4v*)(xr+36));
    #pragma unroll
    for (int t = 0; t < 4; ++t) {
      const float* wr = ws + (16*t + c)*64 + 8*lq;   // Wqa1
      s8v w0 = pack8(*(const f4v*)wr,       *(const f4v*)(wr+4));
      s8v w1 = pack8(*(const f4v*)(wr+32),  *(const f4v*)(wr+36));
      const float bb = bqa[16*t + c];
      f4v acc = {bb, bb, bb, bb};
      acc = MFMA(rA0, w0, acc);
      acc = MFMA(rA1, w1, acc);
      if (lq < 2) {
        #pragma unroll
        for (int r = 0; r < 4; ++r)
          qbuf[(4*lq + r)*HSTRIDE + 16*t + c] = f2bf(acc[r]);
      }
    }
  }

  // ---- prefetch point 0: RAW registers, pack deferred to consumption ----
  f4v nxr0, nxr1, nxr2, nxr3;
  float nza[3], nzb[3];
  {
    const float* xr = x + ptbase * (long)(NK*NC) + c*NC + 8*lq;
    nxr0 = *(const f4v*)xr;      nxr1 = *(const f4v*)(xr+4);
    nxr2 = *(const f4v*)(xr+32); nxr3 = *(const f4v*)(xr+36);
    const float* zp = xyz + ptbase * (long)(NK*3);
    nza[0] = zp[c*3+0]; nza[1] = zp[c*3+1]; nza[2] = zp[c*3+2];
    nzb[0] = zp[0];     nzb[1] = zp[1];     nzb[2] = zp[2];
  }

  // ---- main loop: one point per iteration (NOT unrolled) ----
  #pragma unroll 1
  for (int p = 0; p < QROWS; ++p) {
    // consume prefetched data (waitcnt lands here, a full body after issue)
    s8v xA0 = pack8(nxr0, nxr1);
    s8v xA1 = pack8(nxr2, nxr3);
    const float rx = nza[0] - nzb[0];
    const float ry = nza[1] - nzb[1];
    const float rz = nza[2] - nzb[2];
    // issue next point's loads immediately (in flight across this body)
    if (p < QROWS-1) {
      const long prow = ptbase + p + 1;
      const float* xr = x + prow * (long)(NK*NC) + c*NC + 8*lq;
      nxr0 = *(const f4v*)xr;      nxr1 = *(const f4v*)(xr+4);
      nxr2 = *(const f4v*)(xr+32); nxr3 = *(const f4v*)(xr+36);
      const float* zp = xyz + prow * (long)(NK*3);
      nza[0] = zp[c*3+0]; nza[1] = zp[c*3+1]; nza[2] = zp[c*3+2];
      nzb[0] = zp[0];     nzb[1] = zp[1];     nzb[2] = zp[2];
    }

    // s[t] = qa + bc + x@Wak'^T   (mat 0)
    f4v s[4];
    #pragma unroll
    for (int t = 0; t < 4; ++t) {
      const short* wb = &wlds[(0*512 + 2*t*64 + lane) * 8];
      s8v w0 = *(const s8v*)wb;
      s8v w1 = *(const s8v*)(wb + 512);
      const float base = bf2f((unsigned short)qbuf[p*HSTRIDE + 16*t + c]) + bcf[t];
      f4v acc = {base, base, base, base};
      acc = MFMA(xA0, w0, acc);
      acc = MFMA(xA1, w1, acc);
      s[t] = acc;
    }

    // vacc = x @ Wv^T + bv   (register frags)
    f4v vacc[4];
    #pragma unroll
    for (int t = 0; t < 4; ++t) {
      f4v acc = {bvf[t], bvf[t], bvf[t], bvf[t]};
      acc = MFMA(xA0, wvf[2*t+0], acc);
      acc = MFMA(xA1, wvf[2*t+1], acc);
      vacc[t] = acc;
    }

    // p1 = relu(Wp1·rel + bp1) via VALU in C-layout; RT (sigma-permuted)
    {
      float rxs[4], rys[4], rzs[4];
      #pragma unroll
      for (int r = 0; r < 4; ++r) {
        rxs[r] = __shfl(rx, 4*lq + r);
        rys[r] = __shfl(ry, 4*lq + r);
        rzs[r] = __shfl(rz, 4*lq + r);
      }
      f4v p1[4];
      #pragma unroll
      for (int t = 0; t < 4; ++t)
        #pragma unroll
        for (int r = 0; r < 4; ++r) {
          float v = bp1f[t] + wp1c[t][0]*rxs[r] + wp1c[t][1]*rys[r] + wp1c[t][2]*rzs[r];
          p1[t][r] = fmaxf(v, 0.0f);
        }
      #pragma unroll
      for (int r = 0; r < 4; ++r) {
        u2v pv = { pk2(p1[0][r], p1[1][r]), pk2(p1[2][r], p1[3][r]) };
        *(u2v*)&hb[(4*lq + r)*HSTRIDE + 4*c] = pv;
      }
    }
    s8v pA0 = *(const s8v*)&hb[c*HSTRIDE + 8*lq];
    s8v pA1 = *(const s8v*)&hb[c*HSTRIDE + 32 + 8*lq];

    // pe = pos1 @ Wp2^T + bp2   (mat 1)
    f4v pe[4];
    #pragma unroll
    for (int t = 0; t < 4; ++t) {
      const short* wb = &wlds[(1*512 + 2*t*64 + lane) * 8];
      s8v w0 = *(const s8v*)wb;
      s8v w1 = *(const s8v*)(wb + 512);
      f4v acc = {bp2f[t], bp2f[t], bp2f[t], bp2f[t]};
      acc = MFMA(pA0, w0, acc);
      acc = MFMA(pA1, w1, acc);
      pe[t] = acc;
    }

    // a1 = relu(s + pos1 @ Wap^T)   (mat 2) ; RT
    #pragma unroll
    for (int t = 0; t < 4; ++t) {
      const short* wb = &wlds[(2*512 + 2*t*64 + lane) * 8];
      s8v w0 = *(const s8v*)wb;
      s8v w1 = *(const s8v*)(wb + 512);
      f4v acc = MFMA(pA0, w0, s[t]);
      acc = MFMA(pA1, w1, acc);
      #pragma unroll
      for (int r = 0; r < 4; ++r) s[t][r] = fmaxf(acc[r], 0.0f);
    }
    #pragma unroll
    for (int r = 0; r < 4; ++r) {
      u2v pv = { pk2(s[0][r], s[1][r]), pk2(s[2][r], s[3][r]) };
      *(u2v*)&hb[(4*lq + r)*HSTRIDE + 4*c] = pv;
    }
    s8v aA0 = *(const s8v*)&hb[c*HSTRIDE + 8*lq];
    s8v aA1 = *(const s8v*)&hb[c*HSTRIDE + 32 + 8*lq];

    // logits = a1 @ Wa2^T + ba2   (mat 3)
    f4v lg[4];
    #pragma unroll
    for (int t = 0; t < 4; ++t) {
      const short* wb = &wlds[(3*512 + 2*t*64 + lane) * 8];
      s8v w0 = *(const s8v*)wb;
      s8v w1 = *(const s8v*)(wb + 512);
      f4v acc = {ba2f[t], ba2f[t], ba2f[t], ba2f[t]};
      acc = MFMA(aA0, w0, acc);
      acc = MFMA(aA1, w1, acc);
      lg[t] = acc;
    }

    // softmax over 16 neighbors + res = sum_m attn*(v+pe)
    #pragma unroll
    for (int t = 0; t < 4; ++t) {
      f4v l = lg[t];
      float mx = fmaxf(fmaxf(l[0], l[1]), fmaxf(l[2], l[3]));
      mx = fmaxf(mx, __shfl_xor(mx, 16));
      mx = fmaxf(mx, __shfl_xor(mx, 32));
      f4v e;
      #pragma unroll
      for (int r = 0; r < 4; ++r) e[r] = exp2f((l[r] - mx) * 0.18033688011112043f);
      float sm = e[0] + e[1] + e[2] + e[3];
      sm += __shfl_xor(sm, 16);
      sm += __shfl_xor(sm, 32);
      const float ri = 1.0f / sm;
      float pr = 0.0f;
      #pragma unroll
      for (int r = 0; r < 4; ++r) pr += (e[r] * ri) * (vacc[t][r] + pe[t][r]);
      pr += __shfl_xor(pr, 16);
      pr += __shfl_xor(pr, 32);
      if (lq == 0) qbuf[p*HSTRIDE + 16*t + c] = f2bf(pr);  // row p: qa[p] is dead
    }
  }

  // ---- group final: out = res @ W2^T + b2 + raw_feature (rows 0..7) ----
  {
    s8v resA0 = *(const s8v*)&qbuf[(c & 7)*HSTRIDE + 8*lq];
    s8v resA1 = *(const s8v*)&qbuf[(c & 7)*HSTRIDE + 32 + 8*lq];
    #pragma unroll
    for (int t = 0; t < 4; ++t) {
      const float* wr = W2 + (16*t + c)*64 + 8*lq;
      s8v w0 = pack8(*(const f4v*)wr,      *(const f4v*)(wr+4));
      s8v w1 = pack8(*(const f4v*)(wr+32), *(const f4v*)(wr+36));
      const float bb = b2[16*t + c];
      f4v acc = {bb, bb, bb, bb};
      acc = MFMA(resA0, w0, acc);
      acc = MFMA(resA1, w1, acc);
      if (lq < 2) {
        #pragma unroll
        for (int r = 0; r < 4; ++r) {
          const long pr2 = ptbase + 4*lq + r;
          out[pr2*NC + 16*t + c] = acc[r] + x[pr2*(long)(NK*NC) + 16*t + c];
        }
      }
    }
  }
}

extern "C" void kernel_launch(void* const* d_in, const int* in_sizes, int n_in,
                              void* d_out, int out_size, void* d_ws, size_t ws_size,
                              hipStream_t stream) {
  (void)in_sizes; (void)n_in; (void)out_size; (void)ws_size;
  const float* x   = (const float*)d_in[0];
  const float* xyz = (const float*)d_in[1];
  const float* Wq  = (const float*)d_in[2];
  const float* bq  = (const float*)d_in[3];
  const float* Wk  = (const float*)d_in[4];
  const float* bk  = (const float*)d_in[5];
  const float* Wv  = (const float*)d_in[6];
  const float* bv  = (const float*)d_in[7];
  const float* Wp1 = (const float*)d_in[8];
  const float* bp1 = (const float*)d_in[9];
  const float* Wp2 = (const float*)d_in[10];
  const float* bp2 = (const float*)d_in[11];
  const float* Wa1 = (const float*)d_in[12];
  const float* ba1 = (const float*)d_in[13];
  const float* Wa2 = (const float*)d_in[14];
  const float* ba2 = (const float*)d_in[15];
  const float* W2  = (const float*)d_in[16];
  const float* b2  = (const float*)d_in[17];
  float* out = (float*)d_out;
  float* ws  = (float*)d_ws;

  // fold Wa1 into Wq/Wk/Wp2 (12416 floats into ws)
  precomp_kernel<<<dim3(49), dim3(256), 0, stream>>>(Wq, bq, Wk, bk, Wp2, bp2, Wa1, ba1, ws);
  // 32768 points / 8 per wave / 4 waves per block = 1024 blocks
  lattn_kernel<<<dim3(1024), dim3(256), 0, stream>>>(
      x, xyz, Wp1, bp1, Wp2, bp2, Wv, bv, Wa2, ba2, W2, b2, ws, out);
}

// Round 7
// 374.064 us; speedup vs baseline: 1.4925x; 1.4925x over previous
//
#include <hip/hip_runtime.h>

#define NM 4096
#define NK 16
#define NC 64

typedef __attribute__((ext_vector_type(8))) short s8v;
typedef __attribute__((ext_vector_type(4))) float f4v;
typedef __attribute__((ext_vector_type(2))) unsigned int u2v;

__device__ __forceinline__ short f2bf(float f) {
  unsigned u = __builtin_bit_cast(unsigned, f);
  u += 0x7fffu + ((u >> 16) & 1u);          // round-to-nearest-even
  return (short)(u >> 16);
}
__device__ __forceinline__ float bf2f(unsigned short s) {
  return __builtin_bit_cast(float, ((unsigned)s) << 16);
}
__device__ __forceinline__ unsigned pk2(float a, float b) {
  return (unsigned)(unsigned short)f2bf(a) | ((unsigned)(unsigned short)f2bf(b) << 16);
}
__device__ __forceinline__ s8v pack8(f4v a, f4v b) {
  s8v r;
  r[0]=f2bf(a[0]); r[1]=f2bf(a[1]); r[2]=f2bf(a[2]); r[3]=f2bf(a[3]);
  r[4]=f2bf(b[0]); r[5]=f2bf(b[1]); r[6]=f2bf(b[2]); r[7]=f2bf(b[3]);
  return r;
}

#define MFMA(a,b,c) __builtin_amdgcn_mfma_f32_16x16x32_bf16((a),(b),(c),0,0,0)

#define HSTRIDE 72                 // shorts per row: 64 + pad, 16B-aligned rows, 2-way-max banks
#define TB (16*HSTRIDE)            // 16-row buffer: 2304 B

// ---------------- pre-kernel: fold Wa1 into Wq/Wk/Wp2 (fp32, exact) --------
// ws layout (floats):
//   [    0.. 4095] Wqa1 = Wa1·Wq        (row-major [i][j])
//   [ 4096.. 8191] Wak' = -Wa1·Wk
//   [ 8192..12287] Wap  = Wa1·Wp2
//   [12288..12351] bqa  = Wa1·bq
//   [12352..12415] bc   = ba1 + Wa1·(bp2-bk)
__global__ void precomp_kernel(const float* __restrict__ Wq, const float* __restrict__ bq,
                               const float* __restrict__ Wk, const float* __restrict__ bk,
                               const float* __restrict__ Wp2,const float* __restrict__ bp2,
                               const float* __restrict__ Wa1,const float* __restrict__ ba1,
                               float* __restrict__ ws) {
  const int gid = blockIdx.x * 256 + threadIdx.x;
  if (gid < 3*4096) {
    const int m = gid >> 12, e = gid & 4095, i = e >> 6, j = e & 63;
    const float* R = Wa1 + i*64;
    float s = 0.f;
    if (m == 0)      { for (int l = 0; l < 64; ++l) s += R[l] * Wq [l*64 + j]; }
    else if (m == 1) { for (int l = 0; l < 64; ++l) s -= R[l] * Wk [l*64 + j]; }
    else             { for (int l = 0; l < 64; ++l) s += R[l] * Wp2[l*64 + j]; }
    ws[gid] = s;
  } else if (gid < 3*4096 + 64) {
    const int i = gid - 3*4096;
    const float* R = Wa1 + i*64;
    float s = 0.f;
    for (int l = 0; l < 64; ++l) s += R[l] * bq[l];
    ws[gid] = s;
  } else if (gid < 3*4096 + 128) {
    const int i = gid - (3*4096 + 64);
    const float* R = Wa1 + i*64;
    float s = ba1[i];
    for (int l = 0; l < 64; ++l) s += R[l] * (bp2[l] - bk[l]);
    ws[gid] = s;
  }
}

// ---------------- main kernel ----------------------------------------------
// a1 = relu(qa + x@Wak'^T + p1@Wap^T + bc) ;  qa = raw@Wqa1^T + bqa
// p1 computed by VALU in C-layout.
// waves_per_eu(2,2): occupancy is LDS-capped at 2 blocks/CU (8 waves) anyway;
// this stops the allocator from spilling down to 128 VGPRs chasing waves it
// can never get (r1-r6 evidence: VGPR pinned 128, 40-100 MB scratch traffic).
__global__ __attribute__((amdgpu_flat_work_group_size(256, 256)))
           __attribute__((amdgpu_waves_per_eu(2, 2)))
void lattn_kernel(const float* __restrict__ x,  const float* __restrict__ xyz,
                  const float* __restrict__ Wp1,const float* __restrict__ bp1,
                  const float* __restrict__ Wp2,const float* __restrict__ bp2,
                  const float* __restrict__ Wv, const float* __restrict__ bv,
                  const float* __restrict__ Wa2,const float* __restrict__ ba2,
                  const float* __restrict__ W2, const float* __restrict__ b2,
                  const float* __restrict__ ws,
                  float* __restrict__ out) {
  // LDS mats: 0=Wak'(nat) 1=Wv(nat) 2=Wp2(sigma) 3=Wap(sigma) 4=Wa2(sigma)
  __shared__ __align__(16) short wlds[5*8*64*8];   // 40960 B
  __shared__ __align__(16) short qres[4*TB];       // 9216 B (qa, then res)
  __shared__ __align__(16) short hbuf[4*TB];       // 9216 B (RT buffer)
  // total 59392 B -> 2 blocks/CU, 8 waves/CU

  const int tid = threadIdx.x;
  const float* wak = ws + 4096;
  const float* wap = ws + 8192;
  const float* bqa = ws + 12288;
  const float* bcv = ws + 12352;

  // ---- stage 5 weight matrices into LDS, bf16, frag-linear ----
  for (int idx = tid; idx < 5*8*64; idx += 256) {
    const int mat = idx >> 9;
    const int rem = idx & 511;
    const int f   = rem >> 6;
    const int ln  = rem & 63;
    const int t = f >> 1, h = f & 1;
    const int cc = ln & 15, qq = ln >> 4;
    const int n = 16*t + cc;
    const float* W = (mat==0) ? wak : (mat==1) ? Wv : (mat==2) ? Wp2 : (mat==3) ? wap : Wa2;
    const bool prm = (mat >= 2);
    s8v v;
    #pragma unroll
    for (int j = 0; j < 8; ++j) {
      int kp = h*32 + qq*8 + j;
      int k = prm ? (((kp & 3) << 4) | (kp >> 2)) : kp;
      v[j] = f2bf(W[n*64 + k]);
    }
    *(s8v*)&wlds[(size_t)idx * 8] = v;
  }
  __syncthreads();

  const int w    = tid >> 6;
  const int lane = tid & 63;
  const int c    = lane & 15;
  const int lq   = lane >> 4;

  const int gw  = blockIdx.x * 4 + w;   // 0..2047 waves
  const int gp0 = gw << 4;              // 16 points per wave
  const int b   = gp0 >> 12;
  const int m0  = gp0 & (NM - 1);

  short* qbuf = qres + w * TB;
  short* hb   = hbuf + w * TB;

  // ---- loop-invariant: Wp1 rows (C-layout: features 16t+c) + biases ----
  float wp1c[4][3];
  float bp1f[4], bvf[4], bp2f[4], ba2f[4], bcf[4];
  #pragma unroll
  for (int t = 0; t < 4; ++t) {
    const int n = 16*t + c;
    wp1c[t][0] = Wp1[n*3+0]; wp1c[t][1] = Wp1[n*3+1]; wp1c[t][2] = Wp1[n*3+2];
    bp1f[t] = bp1[n]; bvf[t] = bv[n]; bp2f[t] = bp2[n];
    ba2f[t] = ba2[n]; bcf[t] = bcv[n];
  }

  const long ptbase = (long)(b * NM + m0);

  // ---- group qa phase: qa = raw @ Wqa1^T + bqa for the 16 points ----
  {
    const float* xr = x + (ptbase + c) * (long)(NK*NC) + 8*lq;  // neighbor-0 row of point c
    s8v rA0 = pack8(*(const f4v*)xr,        *(const f4v*)(xr+4));
    s8v rA1 = pack8(*(const f4v*)(xr+32),   *(const f4v*)(xr+36));
    #pragma unroll
    for (int t = 0; t < 4; ++t) {
      const float* wr = ws + (16*t + c)*64 + 8*lq;   // Wqa1
      s8v w0 = pack8(*(const f4v*)wr,       *(const f4v*)(wr+4));
      s8v w1 = pack8(*(const f4v*)(wr+32),  *(const f4v*)(wr+36));
      const float bb = bqa[16*t + c];
      f4v acc = {bb, bb, bb, bb};
      acc = MFMA(rA0, w0, acc);
      acc = MFMA(rA1, w1, acc);
      #pragma unroll
      for (int r = 0; r < 4; ++r)
        qbuf[(4*lq + r)*HSTRIDE + 16*t + c] = f2bf(acc[r]);
    }
  }

  // ---- prefetch point 0: RAW registers, pack deferred to consumption ----
  f4v nxr0, nxr1, nxr2, nxr3;
  float nza[3], nzb[3];
  {
    const float* xr = x + ptbase * (long)(NK*NC) + c*NC + 8*lq;
    nxr0 = *(const f4v*)xr;      nxr1 = *(const f4v*)(xr+4);
    nxr2 = *(const f4v*)(xr+32); nxr3 = *(const f4v*)(xr+36);
    const float* zp = xyz + ptbase * (long)(NK*3);
    nza[0] = zp[c*3+0]; nza[1] = zp[c*3+1]; nza[2] = zp[c*3+2];
    nzb[0] = zp[0];     nzb[1] = zp[1];     nzb[2] = zp[2];
  }

  // ---- main loop: one point per iteration (NOT unrolled: register pressure) ----
  #pragma unroll 1
  for (int p = 0; p < 16; ++p) {
    // consume prefetched data (vmcnt wait lands here, a full body after issue)
    s8v xA0 = pack8(nxr0, nxr1);
    s8v xA1 = pack8(nxr2, nxr3);
    const float rx = nza[0] - nzb[0];
    const float ry = nza[1] - nzb[1];
    const float rz = nza[2] - nzb[2];
    // issue next point's loads immediately (in flight across this body)
    if (p < 15) {
      const long prow = ptbase + p + 1;
      const float* xr = x + prow * (long)(NK*NC) + c*NC + 8*lq;
      nxr0 = *(const f4v*)xr;      nxr1 = *(const f4v*)(xr+4);
      nxr2 = *(const f4v*)(xr+32); nxr3 = *(const f4v*)(xr+36);
      const float* zp = xyz + prow * (long)(NK*3);
      nza[0] = zp[c*3+0]; nza[1] = zp[c*3+1]; nza[2] = zp[c*3+2];
      nzb[0] = zp[0];     nzb[1] = zp[1];     nzb[2] = zp[2];
    }

    // s[t] = qa + bc + x@Wak'^T   (mat 0, chain-independent of RT)
    f4v s[4];
    #pragma unroll
    for (int t = 0; t < 4; ++t) {
      const short* wb = &wlds[(0*512 + 2*t*64 + lane) * 8];
      s8v w0 = *(const s8v*)wb;
      s8v w1 = *(const s8v*)(wb + 512);
      const float base = bf2f((unsigned short)qbuf[p*HSTRIDE + 16*t + c]) + bcf[t];
      f4v acc = {base, base, base, base};
      acc = MFMA(xA0, w0, acc);
      acc = MFMA(xA1, w1, acc);
      s[t] = acc;
    }

    // vacc = x @ Wv^T + bv   (mat 1, chain-independent)
    f4v vacc[4];
    #pragma unroll
    for (int t = 0; t < 4; ++t) {
      const short* wb = &wlds[(1*512 + 2*t*64 + lane) * 8];
      s8v w0 = *(const s8v*)wb;
      s8v w1 = *(const s8v*)(wb + 512);
      f4v acc = {bvf[t], bvf[t], bvf[t], bvf[t]};
      acc = MFMA(xA0, w0, acc);
      acc = MFMA(xA1, w1, acc);
      vacc[t] = acc;
    }

    // p1 = relu(Wp1·rel + bp1) via VALU in C-layout; RT (sigma-permuted)
    {
      float rxs[4], rys[4], rzs[4];
      #pragma unroll
      for (int r = 0; r < 4; ++r) {
        rxs[r] = __shfl(rx, 4*lq + r);
        rys[r] = __shfl(ry, 4*lq + r);
        rzs[r] = __shfl(rz, 4*lq + r);
      }
      f4v p1[4];
      #pragma unroll
      for (int t = 0; t < 4; ++t)
        #pragma unroll
        for (int r = 0; r < 4; ++r) {
          float v = bp1f[t] + wp1c[t][0]*rxs[r] + wp1c[t][1]*rys[r] + wp1c[t][2]*rzs[r];
          p1[t][r] = fmaxf(v, 0.0f);
        }
      #pragma unroll
      for (int r = 0; r < 4; ++r) {
        u2v pv = { pk2(p1[0][r], p1[1][r]), pk2(p1[2][r], p1[3][r]) };
        *(u2v*)&hb[(4*lq + r)*HSTRIDE + 4*c] = pv;
      }
    }
    s8v pA0 = *(const s8v*)&hb[c*HSTRIDE + 8*lq];
    s8v pA1 = *(const s8v*)&hb[c*HSTRIDE + 32 + 8*lq];

    // pe = pos1 @ Wp2^T + bp2   (mat 2)
    f4v pe[4];
    #pragma unroll
    for (int t = 0; t < 4; ++t) {
      const short* wb = &wlds[(2*512 + 2*t*64 + lane) * 8];
      s8v w0 = *(const s8v*)wb;
      s8v w1 = *(const s8v*)(wb + 512);
      f4v acc = {bp2f[t], bp2f[t], bp2f[t], bp2f[t]};
      acc = MFMA(pA0, w0, acc);
      acc = MFMA(pA1, w1, acc);
      pe[t] = acc;
    }

    // a1 = relu(s + pos1 @ Wap^T)   (mat 3) ; RT
    #pragma unroll
    for (int t = 0; t < 4; ++t) {
      const short* wb = &wlds[(3*512 + 2*t*64 + lane) * 8];
      s8v w0 = *(const s8v*)wb;
      s8v w1 = *(const s8v*)(wb + 512);
      f4v acc = MFMA(pA0, w0, s[t]);
      acc = MFMA(pA1, w1, acc);
      #pragma unroll
      for (int r = 0; r < 4; ++r) s[t][r] = fmaxf(acc[r], 0.0f);
    }
    #pragma unroll
    for (int r = 0; r < 4; ++r) {
      u2v pv = { pk2(s[0][r], s[1][r]), pk2(s[2][r], s[3][r]) };
      *(u2v*)&hb[(4*lq + r)*HSTRIDE + 4*c] = pv;
    }
    s8v aA0 = *(const s8v*)&hb[c*HSTRIDE + 8*lq];
    s8v aA1 = *(const s8v*)&hb[c*HSTRIDE + 32 + 8*lq];

    // logits = a1 @ Wa2^T + ba2   (mat 4)
    f4v lg[4];
    #pragma unroll
    for (int t = 0; t < 4; ++t) {
      const short* wb = &wlds[(4*512 + 2*t*64 + lane) * 8];
      s8v w0 = *(const s8v*)wb;
      s8v w1 = *(const s8v*)(wb + 512);
      f4v acc = {ba2f[t], ba2f[t], ba2f[t], ba2f[t]};
      acc = MFMA(aA0, w0, acc);
      acc = MFMA(aA1, w1, acc);
      lg[t] = acc;
    }

    // softmax over 16 neighbors (C rows), per feature column; scale 1/8
    // then res = sum_m attn * (v + pe)
    #pragma unroll
    for (int t = 0; t < 4; ++t) {
      f4v l = lg[t];
      float mx = fmaxf(fmaxf(l[0], l[1]), fmaxf(l[2], l[3]));
      mx = fmaxf(mx, __shfl_xor(mx, 16));
      mx = fmaxf(mx, __shfl_xor(mx, 32));
      f4v e;
      #pragma unroll
      for (int r = 0; r < 4; ++r) e[r] = exp2f((l[r] - mx) * 0.18033688011112043f);
      float sm = e[0] + e[1] + e[2] + e[3];
      sm += __shfl_xor(sm, 16);
      sm += __shfl_xor(sm, 32);
      const float ri = 1.0f / sm;
      float pr = 0.0f;
      #pragma unroll
      for (int r = 0; r < 4; ++r) pr += (e[r] * ri) * (vacc[t][r] + pe[t][r]);
      pr += __shfl_xor(pr, 16);
      pr += __shfl_xor(pr, 32);
      if (lq == 0) qbuf[p*HSTRIDE + 16*t + c] = f2bf(pr);  // row p: qa[p] is dead
    }
  }

  // ---- group final: out = res @ W2^T + b2 + raw_feature ----
  {
    s8v resA0 = *(const s8v*)&qbuf[c*HSTRIDE + 8*lq];
    s8v resA1 = *(const s8v*)&qbuf[c*HSTRIDE + 32 + 8*lq];
    #pragma unroll
    for (int t = 0; t < 4; ++t) {
      const float* wr = W2 + (16*t + c)*64 + 8*lq;
      s8v w0 = pack8(*(const f4v*)wr,      *(const f4v*)(wr+4));
      s8v w1 = pack8(*(const f4v*)(wr+32), *(const f4v*)(wr+36));
      const float bb = b2[16*t + c];
      f4v acc = {bb, bb, bb, bb};
      acc = MFMA(resA0, w0, acc);
      acc = MFMA(resA1, w1, acc);
      #pragma unroll
      for (int r = 0; r < 4; ++r) {
        const long pr2 = ptbase + 4*lq + r;
        out[pr2*NC + 16*t + c] = acc[r] + x[pr2*(long)(NK*NC) + 16*t + c];
      }
    }
  }
}

extern "C" void kernel_launch(void* const* d_in, const int* in_sizes, int n_in,
                              void* d_out, int out_size, void* d_ws, size_t ws_size,
                              hipStream_t stream) {
  (void)in_sizes; (void)n_in; (void)out_size; (void)ws_size;
  const float* x   = (const float*)d_in[0];
  const float* xyz = (const float*)d_in[1];
  const float* Wq  = (const float*)d_in[2];
  const float* bq  = (const float*)d_in[3];
  const float* Wk  = (const float*)d_in[4];
  const float* bk  = (const float*)d_in[5];
  const float* Wv  = (const float*)d_in[6];
  const float* bv  = (const float*)d_in[7];
  const float* Wp1 = (const float*)d_in[8];
  const float* bp1 = (const float*)d_in[9];
  const float* Wp2 = (const float*)d_in[10];
  const float* bp2 = (const float*)d_in[11];
  const float* Wa1 = (const float*)d_in[12];
  const float* ba1 = (const float*)d_in[13];
  const float* Wa2 = (const float*)d_in[14];
  const float* ba2 = (const float*)d_in[15];
  const float* W2  = (const float*)d_in[16];
  const float* b2  = (const float*)d_in[17];
  float* out = (float*)d_out;
  float* ws  = (float*)d_ws;

  // fold Wa1 into Wq/Wk/Wp2 (12416 floats into ws)
  precomp_kernel<<<dim3(49), dim3(256), 0, stream>>>(Wq, bq, Wk, bk, Wp2, bp2, Wa1, ba1, ws);
  // 32768 points / 16 per wave / 4 waves per block = 512 blocks
  lattn_kernel<<<dim3(512), dim3(256), 0, stream>>>(
      x, xyz, Wp1, bp1, Wp2, bp2, Wv, bv, Wa2, ba2, W2, b2, ws, out);
}

// Round 8
// 290.770 us; speedup vs baseline: 1.9201x; 1.2865x over previous
//
#include <hip/hip_runtime.h>

#define NM 4096
#define NK 16
#define NC 64

typedef __attribute__((ext_vector_type(8))) short s8v;
typedef __attribute__((ext_vector_type(4))) float f4v;
typedef __attribute__((ext_vector_type(2))) unsigned int u2v;

__device__ __forceinline__ short f2bf(float f) {
  unsigned u = __builtin_bit_cast(unsigned, f);
  u += 0x7fffu + ((u >> 16) & 1u);          // round-to-nearest-even
  return (short)(u >> 16);
}
__device__ __forceinline__ float bf2f(unsigned short s) {
  return __builtin_bit_cast(float, ((unsigned)s) << 16);
}
__device__ __forceinline__ unsigned pk2(float a, float b) {
  return (unsigned)(unsigned short)f2bf(a) | ((unsigned)(unsigned short)f2bf(b) << 16);
}
__device__ __forceinline__ s8v pack8(f4v a, f4v b) {
  s8v r;
  r[0]=f2bf(a[0]); r[1]=f2bf(a[1]); r[2]=f2bf(a[2]); r[3]=f2bf(a[3]);
  r[4]=f2bf(b[0]); r[5]=f2bf(b[1]); r[6]=f2bf(b[2]); r[7]=f2bf(b[3]);
  return r;
}

#define MFMA(a,b,c) __builtin_amdgcn_mfma_f32_16x16x32_bf16((a),(b),(c),0,0,0)

#define HSTRIDE 72                 // shorts per row: 64 + pad, 16B-aligned rows, 2-way-max banks
#define TB (16*HSTRIDE)            // 16-row buffer: 2304 B

// ---------------- pre-kernel: fold Wa1 into Wq/Wk/Wp2 (fp32, exact) --------
// ws layout (floats):
//   [    0.. 4095] Wqa1 = Wa1·Wq        (row-major [i][j])
//   [ 4096.. 8191] Wak' = -Wa1·Wk
//   [ 8192..12287] Wap  = Wa1·Wp2
//   [12288..12351] bqa  = Wa1·bq
//   [12352..12415] bc   = ba1 + Wa1·(bp2-bk)
__global__ void precomp_kernel(const float* __restrict__ Wq, const float* __restrict__ bq,
                               const float* __restrict__ Wk, const float* __restrict__ bk,
                               const float* __restrict__ Wp2,const float* __restrict__ bp2,
                               const float* __restrict__ Wa1,const float* __restrict__ ba1,
                               float* __restrict__ ws) {
  const int gid = blockIdx.x * 256 + threadIdx.x;
  if (gid < 3*4096) {
    const int m = gid >> 12, e = gid & 4095, i = e >> 6, j = e & 63;
    const float* R = Wa1 + i*64;
    float s = 0.f;
    if (m == 0)      { for (int l = 0; l < 64; ++l) s += R[l] * Wq [l*64 + j]; }
    else if (m == 1) { for (int l = 0; l < 64; ++l) s -= R[l] * Wk [l*64 + j]; }
    else             { for (int l = 0; l < 64; ++l) s += R[l] * Wp2[l*64 + j]; }
    ws[gid] = s;
  } else if (gid < 3*4096 + 64) {
    const int i = gid - 3*4096;
    const float* R = Wa1 + i*64;
    float s = 0.f;
    for (int l = 0; l < 64; ++l) s += R[l] * bq[l];
    ws[gid] = s;
  } else if (gid < 3*4096 + 128) {
    const int i = gid - (3*4096 + 64);
    const float* R = Wa1 + i*64;
    float s = ba1[i];
    for (int l = 0; l < 64; ++l) s += R[l] * (bp2[l] - bk[l]);
    ws[gid] = s;
  }
}

// ---------------- main kernel ----------------------------------------------
// a1 = relu(qa + x@Wak'^T + p1@Wap^T + bc) ;  qa = raw@Wqa1^T + bqa
// p1 computed by VALU in C-layout.
// waves_per_eu(1,8): min=1 lifts the arch-VGPR budget (empirical cap was
// 256/min_waves: r3 min4->64, r6 min3->84, r1/r5/r7 min2->128 — every one
// spilled). Physical tier (m69) allows 2 waves/SIMD up to 256 regs, and we
// are LDS-capped at 2 blocks/CU anyway, so letting VGPRs float to ~200
// costs no occupancy and removes the scratch traffic that is the wall.
__global__ __attribute__((amdgpu_flat_work_group_size(256, 256)))
           __attribute__((amdgpu_waves_per_eu(1, 8)))
void lattn_kernel(const float* __restrict__ x,  const float* __restrict__ xyz,
                  const float* __restrict__ Wp1,const float* __restrict__ bp1,
                  const float* __restrict__ Wp2,const float* __restrict__ bp2,
                  const float* __restrict__ Wv, const float* __restrict__ bv,
                  const float* __restrict__ Wa2,const float* __restrict__ ba2,
                  const float* __restrict__ W2, const float* __restrict__ b2,
                  const float* __restrict__ ws,
                  float* __restrict__ out) {
  // LDS mats: 0=Wak'(nat) 1=Wv(nat) 2=Wp2(sigma) 3=Wap(sigma) 4=Wa2(sigma)
  __shared__ __align__(16) short wlds[5*8*64*8];   // 40960 B
  __shared__ __align__(16) short qres[4*TB];       // 9216 B (qa, then res)
  __shared__ __align__(16) short hbuf[4*TB];       // 9216 B (RT buffer)
  // total 59392 B -> 2 blocks/CU, 8 waves/CU

  const int tid = threadIdx.x;
  const float* wak = ws + 4096;
  const float* wap = ws + 8192;
  const float* bqa = ws + 12288;
  const float* bcv = ws + 12352;

  // ---- stage 5 weight matrices into LDS, bf16, frag-linear ----
  for (int idx = tid; idx < 5*8*64; idx += 256) {
    const int mat = idx >> 9;
    const int rem = idx & 511;
    const int f   = rem >> 6;
    const int ln  = rem & 63;
    const int t = f >> 1, h = f & 1;
    const int cc = ln & 15, qq = ln >> 4;
    const int n = 16*t + cc;
    const float* W = (mat==0) ? wak : (mat==1) ? Wv : (mat==2) ? Wp2 : (mat==3) ? wap : Wa2;
    const bool prm = (mat >= 2);
    s8v v;
    #pragma unroll
    for (int j = 0; j < 8; ++j) {
      int kp = h*32 + qq*8 + j;
      int k = prm ? (((kp & 3) << 4) | (kp >> 2)) : kp;
      v[j] = f2bf(W[n*64 + k]);
    }
    *(s8v*)&wlds[(size_t)idx * 8] = v;
  }
  __syncthreads();

  const int w    = tid >> 6;
  const int lane = tid & 63;
  const int c    = lane & 15;
  const int lq   = lane >> 4;

  const int gw  = blockIdx.x * 4 + w;   // 0..2047 waves
  const int gp0 = gw << 4;              // 16 points per wave
  const int b   = gp0 >> 12;
  const int m0  = gp0 & (NM - 1);

  short* qbuf = qres + w * TB;
  short* hb   = hbuf + w * TB;

  // ---- loop-invariant: Wp1 rows (C-layout: features 16t+c) + biases ----
  float wp1c[4][3];
  float bp1f[4], bvf[4], bp2f[4], ba2f[4], bcf[4];
  #pragma unroll
  for (int t = 0; t < 4; ++t) {
    const int n = 16*t + c;
    wp1c[t][0] = Wp1[n*3+0]; wp1c[t][1] = Wp1[n*3+1]; wp1c[t][2] = Wp1[n*3+2];
    bp1f[t] = bp1[n]; bvf[t] = bv[n]; bp2f[t] = bp2[n];
    ba2f[t] = ba2[n]; bcf[t] = bcv[n];
  }

  const long ptbase = (long)(b * NM + m0);

  // ---- group qa phase: qa = raw @ Wqa1^T + bqa for the 16 points ----
  {
    const float* xr = x + (ptbase + c) * (long)(NK*NC) + 8*lq;  // neighbor-0 row of point c
    s8v rA0 = pack8(*(const f4v*)xr,        *(const f4v*)(xr+4));
    s8v rA1 = pack8(*(const f4v*)(xr+32),   *(const f4v*)(xr+36));
    #pragma unroll
    for (int t = 0; t < 4; ++t) {
      const float* wr = ws + (16*t + c)*64 + 8*lq;   // Wqa1
      s8v w0 = pack8(*(const f4v*)wr,       *(const f4v*)(wr+4));
      s8v w1 = pack8(*(const f4v*)(wr+32),  *(const f4v*)(wr+36));
      const float bb = bqa[16*t + c];
      f4v acc = {bb, bb, bb, bb};
      acc = MFMA(rA0, w0, acc);
      acc = MFMA(rA1, w1, acc);
      #pragma unroll
      for (int r = 0; r < 4; ++r)
        qbuf[(4*lq + r)*HSTRIDE + 16*t + c] = f2bf(acc[r]);
    }
  }

  // ---- prefetch point 0: RAW registers, pack deferred to consumption ----
  f4v nxr0, nxr1, nxr2, nxr3;
  float nza[3], nzb[3];
  {
    const float* xr = x + ptbase * (long)(NK*NC) + c*NC + 8*lq;
    nxr0 = *(const f4v*)xr;      nxr1 = *(const f4v*)(xr+4);
    nxr2 = *(const f4v*)(xr+32); nxr3 = *(const f4v*)(xr+36);
    const float* zp = xyz + ptbase * (long)(NK*3);
    nza[0] = zp[c*3+0]; nza[1] = zp[c*3+1]; nza[2] = zp[c*3+2];
    nzb[0] = zp[0];     nzb[1] = zp[1];     nzb[2] = zp[2];
  }

  // ---- main loop: one point per iteration (NOT unrolled: register pressure) ----
  #pragma unroll 1
  for (int p = 0; p < 16; ++p) {
    // consume prefetched data (vmcnt wait lands here, a full body after issue)
    s8v xA0 = pack8(nxr0, nxr1);
    s8v xA1 = pack8(nxr2, nxr3);
    const float rx = nza[0] - nzb[0];
    const float ry = nza[1] - nzb[1];
    const float rz = nza[2] - nzb[2];
    // issue next point's loads immediately (in flight across this body)
    if (p < 15) {
      const long prow = ptbase + p + 1;
      const float* xr = x + prow * (long)(NK*NC) + c*NC + 8*lq;
      nxr0 = *(const f4v*)xr;      nxr1 = *(const f4v*)(xr+4);
      nxr2 = *(const f4v*)(xr+32); nxr3 = *(const f4v*)(xr+36);
      const float* zp = xyz + prow * (long)(NK*3);
      nza[0] = zp[c*3+0]; nza[1] = zp[c*3+1]; nza[2] = zp[c*3+2];
      nzb[0] = zp[0];     nzb[1] = zp[1];     nzb[2] = zp[2];
    }

    // s[t] = qa + bc + x@Wak'^T   (mat 0, chain-independent of RT)
    f4v s[4];
    #pragma unroll
    for (int t = 0; t < 4; ++t) {
      const short* wb = &wlds[(0*512 + 2*t*64 + lane) * 8];
      s8v w0 = *(const s8v*)wb;
      s8v w1 = *(const s8v*)(wb + 512);
      const float base = bf2f((unsigned short)qbuf[p*HSTRIDE + 16*t + c]) + bcf[t];
      f4v acc = {base, base, base, base};
      acc = MFMA(xA0, w0, acc);
      acc = MFMA(xA1, w1, acc);
      s[t] = acc;
    }

    // p1 = relu(Wp1·rel + bp1) via VALU in C-layout; RT (sigma-permuted)
    {
      float rxs[4], rys[4], rzs[4];
      #pragma unroll
      for (int r = 0; r < 4; ++r) {
        rxs[r] = __shfl(rx, 4*lq + r);
        rys[r] = __shfl(ry, 4*lq + r);
        rzs[r] = __shfl(rz, 4*lq + r);
      }
      f4v p1[4];
      #pragma unroll
      for (int t = 0; t < 4; ++t)
        #pragma unroll
        for (int r = 0; r < 4; ++r) {
          float v = bp1f[t] + wp1c[t][0]*rxs[r] + wp1c[t][1]*rys[r] + wp1c[t][2]*rzs[r];
          p1[t][r] = fmaxf(v, 0.0f);
        }
      #pragma unroll
      for (int r = 0; r < 4; ++r) {
        u2v pv = { pk2(p1[0][r], p1[1][r]), pk2(p1[2][r], p1[3][r]) };
        *(u2v*)&hb[(4*lq + r)*HSTRIDE + 4*c] = pv;
      }
    }
    s8v pA0 = *(const s8v*)&hb[c*HSTRIDE + 8*lq];
    s8v pA1 = *(const s8v*)&hb[c*HSTRIDE + 32 + 8*lq];

    // pe = pos1 @ Wp2^T + bp2   (mat 2)
    f4v pe[4];
    #pragma unroll
    for (int t = 0; t < 4; ++t) {
      const short* wb = &wlds[(2*512 + 2*t*64 + lane) * 8];
      s8v w0 = *(const s8v*)wb;
      s8v w1 = *(const s8v*)(wb + 512);
      f4v acc = {bp2f[t], bp2f[t], bp2f[t], bp2f[t]};
      acc = MFMA(pA0, w0, acc);
      acc = MFMA(pA1, w1, acc);
      pe[t] = acc;
    }

    // a1 = relu(s + pos1 @ Wap^T)   (mat 3) ; RT
    #pragma unroll
    for (int t = 0; t < 4; ++t) {
      const short* wb = &wlds[(3*512 + 2*t*64 + lane) * 8];
      s8v w0 = *(const s8v*)wb;
      s8v w1 = *(const s8v*)(wb + 512);
      f4v acc = MFMA(pA0, w0, s[t]);
      acc = MFMA(pA1, w1, acc);
      #pragma unroll
      for (int r = 0; r < 4; ++r) s[t][r] = fmaxf(acc[r], 0.0f);
    }
    #pragma unroll
    for (int r = 0; r < 4; ++r) {
      u2v pv = { pk2(s[0][r], s[1][r]), pk2(s[2][r], s[3][r]) };
      *(u2v*)&hb[(4*lq + r)*HSTRIDE + 4*c] = pv;
    }
    s8v aA0 = *(const s8v*)&hb[c*HSTRIDE + 8*lq];
    s8v aA1 = *(const s8v*)&hb[c*HSTRIDE + 32 + 8*lq];

    // vacc = x @ Wv^T + bv   (mat 1) — placed late to shorten its live span;
    // chain-independent (needs only xA), overlaps the aA round-trip wait.
    f4v vacc[4];
    #pragma unroll
    for (int t = 0; t < 4; ++t) {
      const short* wb = &wlds[(1*512 + 2*t*64 + lane) * 8];
      s8v w0 = *(const s8v*)wb;
      s8v w1 = *(const s8v*)(wb + 512);
      f4v acc = {bvf[t], bvf[t], bvf[t], bvf[t]};
      acc = MFMA(xA0, w0, acc);
      acc = MFMA(xA1, w1, acc);
      vacc[t] = acc;
    }

    // logits = a1 @ Wa2^T + ba2   (mat 4)
    f4v lg[4];
    #pragma unroll
    for (int t = 0; t < 4; ++t) {
      const short* wb = &wlds[(4*512 + 2*t*64 + lane) * 8];
      s8v w0 = *(const s8v*)wb;
      s8v w1 = *(const s8v*)(wb + 512);
      f4v acc = {ba2f[t], ba2f[t], ba2f[t], ba2f[t]};
      acc = MFMA(aA0, w0, acc);
      acc = MFMA(aA1, w1, acc);
      lg[t] = acc;
    }

    // softmax over 16 neighbors (C rows), per feature column; scale 1/8
    // then res = sum_m attn * (v + pe)
    #pragma unroll
    for (int t = 0; t < 4; ++t) {
      f4v l = lg[t];
      float mx = fmaxf(fmaxf(l[0], l[1]), fmaxf(l[2], l[3]));
      mx = fmaxf(mx, __shfl_xor(mx, 16));
      mx = fmaxf(mx, __shfl_xor(mx, 32));
      f4v e;
      #pragma unroll
      for (int r = 0; r < 4; ++r) e[r] = exp2f((l[r] - mx) * 0.18033688011112043f);
      float sm = e[0] + e[1] + e[2] + e[3];
      sm += __shfl_xor(sm, 16);
      sm += __shfl_xor(sm, 32);
      const float ri = 1.0f / sm;
      float pr = 0.0f;
      #pragma unroll
      for (int r = 0; r < 4; ++r) pr += (e[r] * ri) * (vacc[t][r] + pe[t][r]);
      pr += __shfl_xor(pr, 16);
      pr += __shfl_xor(pr, 32);
      if (lq == 0) qbuf[p*HSTRIDE + 16*t + c] = f2bf(pr);  // row p: qa[p] is dead
    }
  }

  // ---- group final: out = res @ W2^T + b2 + raw_feature ----
  {
    s8v resA0 = *(const s8v*)&qbuf[c*HSTRIDE + 8*lq];
    s8v resA1 = *(const s8v*)&qbuf[c*HSTRIDE + 32 + 8*lq];
    #pragma unroll
    for (int t = 0; t < 4; ++t) {
      const float* wr = W2 + (16*t + c)*64 + 8*lq;
      s8v w0 = pack8(*(const f4v*)wr,      *(const f4v*)(wr+4));
      s8v w1 = pack8(*(const f4v*)(wr+32), *(const f4v*)(wr+36));
      const float bb = b2[16*t + c];
      f4v acc = {bb, bb, bb, bb};
      acc = MFMA(resA0, w0, acc);
      acc = MFMA(resA1, w1, acc);
      #pragma unroll
      for (int r = 0; r < 4; ++r) {
        const long pr2 = ptbase + 4*lq + r;
        out[pr2*NC + 16*t + c] = acc[r] + x[pr2*(long)(NK*NC) + 16*t + c];
      }
    }
  }
}

extern "C" void kernel_launch(void* const* d_in, const int* in_sizes, int n_in,
                              void* d_out, int out_size, void* d_ws, size_t ws_size,
                              hipStream_t stream) {
  (void)in_sizes; (void)n_in; (void)out_size; (void)ws_size;
  const float* x   = (const float*)d_in[0];
  const float* xyz = (const float*)d_in[1];
  const float* Wq  = (const float*)d_in[2];
  const float* bq  = (const float*)d_in[3];
  const float* Wk  = (const float*)d_in[4];
  const float* bk  = (const float*)d_in[5];
  const float* Wv  = (const float*)d_in[6];
  const float* bv  = (const float*)d_in[7];
  const float* Wp1 = (const float*)d_in[8];
  const float* bp1 = (const float*)d_in[9];
  const float* Wp2 = (const float*)d_in[10];
  const float* bp2 = (const float*)d_in[11];
  const float* Wa1 = (const float*)d_in[12];
  const float* ba1 = (const float*)d_in[13];
  const float* Wa2 = (const float*)d_in[14];
  const float* ba2 = (const float*)d_in[15];
  const float* W2  = (const float*)d_in[16];
  const float* b2  = (const float*)d_in[17];
  float* out = (float*)d_out;
  float* ws  = (float*)d_ws;

  // fold Wa1 into Wq/Wk/Wp2 (12416 floats into ws)
  precomp_kernel<<<dim3(49), dim3(256), 0, stream>>>(Wq, bq, Wk, bk, Wp2, bp2, Wa1, ba1, ws);
  // 32768 points / 16 per wave / 4 waves per block = 512 blocks
  lattn_kernel<<<dim3(512), dim3(256), 0, stream>>>(
      x, xyz, Wp1, bp1, Wp2, bp2, Wv, bv, Wa2, ba2, W2, b2, ws, out);
}